// Round 7
// baseline (273.252 us; speedup 1.0000x reference)
//
#include <hip/hip_runtime.h>
#include <hip/hip_bf16.h>
#include <cstdint>
#include <cstddef>
#include <type_traits>

// FocalAttention: B=4 T=2048 D=1024 H=16 hd=64 RADIUS=4 (banded, 9-wide window)
// fp32 in/out. cvt(fp32->bf16) -> gemm_qkv (A-in-registers, B-only LDS) ->
// banded attn (4 threads/query) -> gemm_proj (2-phase 128x128, 2 blocks/CU).
// r8: sched_barrier(0) everywhere = m141 regression. r9: exact-round grids.
// r13: 2-phase+counted-vmcnt+2 blocks/CU = 59.8us qkv. r14: same for proj (works).
// r15 (this round): qkv was LDS-BW-bound: A-slab ds_reads duplicated 4x across
//   wn-waves (224KB rd + 80KB wr = 2432 cyc/CU/K-tile vs MFMA 1862; sum ~= wall).
//   Fix: A fragments load global->VGPR directly (32 VGPR/wave, L1/L2-resident;
//   panels 2MB/XCD under swizzle). LDS now B-only (48KB): 144KB/K-tile = 1125cyc.
//   Sync simplifies to ONE barrier/K-tile: {STAGE_B(t+1); 6 ds_read; lgkm0;
//   24 MFMA; LDA(t+1); vmcnt(0); BAR}. Stage is in flight across the MFMA
//   cluster (>=1800cyc > 900 HBM) so vmcnt(0) is ~free; cross-wave WAR holds
//   because every wave's lgkm0 precedes its BAR arrival (program order).

typedef __hip_bfloat16 bf16;
typedef __attribute__((ext_vector_type(8))) short bf16x8;   // A/B frag: 8 bf16 = 4 VGPRs
typedef __attribute__((ext_vector_type(4))) float f32x4;    // C/D frag
typedef __attribute__((ext_vector_type(8))) unsigned short u16x8;

#define BATCH  4
#define SEQ    2048
#define DIM    1024
#define NHEAD  16
#define HDIM   64
#define RADIUS 4
#define ROWS   (BATCH * SEQ)          // 8192
#define KDIM   1024
#define NT     (KDIM / 64)            // 16 K-tiles
#define HSLICE (SEQ * HDIM)           // elems per (b,h,s) slice

__device__ __forceinline__ void async_copy16(const void* gptr, void* lptr) {
    __builtin_amdgcn_global_load_lds(
        (const __attribute__((address_space(1))) unsigned int*)(uintptr_t)gptr,
        (__attribute__((address_space(3))) unsigned int*)(uint32_t)(uintptr_t)lptr,
        16, 0, 0);
}

// Fused fp32 -> bf16 convert for all three tensors, 8 elems/thread.
__global__ __launch_bounds__(256)
void cvt_all(const float* __restrict__ s1, bf16* __restrict__ d1, int n1,
             const float* __restrict__ s2, bf16* __restrict__ d2, int n2,
             const float* __restrict__ s3, bf16* __restrict__ d3, int n3) {
    int i = blockIdx.x * blockDim.x + threadIdx.x;
    const float* src; bf16* dst;
    if (i < n1)              { src = s1; dst = d1; }
    else if (i < n1 + n2)    { i -= n1; src = s2; dst = d2; }
    else if (i < n1+n2+n3)   { i -= n1 + n2; src = s3; dst = d3; }
    else return;
    const float4 a = ((const float4*)src)[2 * i];
    const float4 b = ((const float4*)src)[2 * i + 1];
    union { u16x8 v; __hip_bfloat16 h[8]; } o;
    o.h[0] = __float2bfloat16(a.x); o.h[1] = __float2bfloat16(a.y);
    o.h[2] = __float2bfloat16(a.z); o.h[3] = __float2bfloat16(a.w);
    o.h[4] = __float2bfloat16(b.x); o.h[5] = __float2bfloat16(b.y);
    o.h[6] = __float2bfloat16(b.z); o.h[7] = __float2bfloat16(b.w);
    ((u16x8*)dst)[i] = o.v;
}

#define BAR()        __builtin_amdgcn_s_barrier()
#define WAIT_LGKM0() asm volatile("s_waitcnt lgkmcnt(0)")

// ---------------------------------------------------------------------------
// gemm_qkv_ar: BM=128 BN=192, A in registers, B-only double-buffered LDS.
// ---------------------------------------------------------------------------

// B tile = 192 rows x 64 k = 24 KB = 3 units of 512 thr x 16 B.
#define STAGE_B3(buf_, kt_) do {                                                \
    _Pragma("unroll")                                                           \
    for (int j_ = 0; j_ < 3; ++j_) {                                            \
        const int c_   = j_ * 512 + tid;                                        \
        const int row_ = c_ >> 3;                                               \
        const int kg_  = (c_ & 7) ^ (row_ & 7);                                 \
        async_copy16(B + (size_t)(tileN + row_) * KDIM + (kt_) + kg_ * 8,       \
                     (char*)Bs[buf_] + c_ * 16);                                \
    } } while (0)

// A fragments straight from global (no swizzle; 4 row-base ptrs + imm offsets).
#define LDA_G(kt_) do {                                                         \
    _Pragma("unroll")                                                           \
    for (int ks_ = 0; ks_ < 2; ++ks_)                                           \
    _Pragma("unroll")                                                           \
    for (int mt_ = 0; mt_ < 4; ++mt_)                                           \
        aF[ks_][mt_] = *(const bf16x8*)(aRow[mt_] + (kt_) + (ks_ << 5));        \
} while (0)

#define LDBA() do {                                                             \
    _Pragma("unroll")                                                           \
    for (int ks_ = 0; ks_ < 2; ++ks_)                                           \
    _Pragma("unroll")                                                           \
    for (int nt_ = 0; nt_ < 2; ++nt_)                                           \
        bFA[ks_][nt_] = *(const bf16x8*)(bs_ +                                  \
            (size_t)(wn * 48 + nt_ * 16 + l16) * 64 +                           \
            ((((ks_ << 2) | quad) ^ hh) << 3));                                 \
} while (0)

#define LDBB() do {                                                             \
    _Pragma("unroll")                                                           \
    for (int ks_ = 0; ks_ < 2; ++ks_)                                           \
        bFB[ks_] = *(const bf16x8*)(bs_ +                                       \
            (size_t)(wn * 48 + 32 + l16) * 64 +                                 \
            ((((ks_ << 2) | quad) ^ hh) << 3));                                 \
} while (0)

#define MFMA_N01() do {                                                         \
    _Pragma("unroll")                                                           \
    for (int ks_ = 0; ks_ < 2; ++ks_)                                           \
    _Pragma("unroll")                                                           \
    for (int mt_ = 0; mt_ < 4; ++mt_)                                           \
    _Pragma("unroll")                                                           \
    for (int nt_ = 0; nt_ < 2; ++nt_)                                           \
        acc[mt_][nt_] = __builtin_amdgcn_mfma_f32_16x16x32_bf16(                \
            aF[ks_][mt_], bFA[ks_][nt_], acc[mt_][nt_], 0, 0, 0);               \
} while (0)

#define MFMA_N2() do {                                                          \
    _Pragma("unroll")                                                           \
    for (int ks_ = 0; ks_ < 2; ++ks_)                                           \
    _Pragma("unroll")                                                           \
    for (int mt_ = 0; mt_ < 4; ++mt_)                                           \
        acc[mt_][2] = __builtin_amdgcn_mfma_f32_16x16x32_bf16(                  \
            aF[ks_][mt_], bFB[ks_], acc[mt_][2], 0, 0, 0);                      \
} while (0)

__global__ __launch_bounds__(512, 4)   // 4 waves/SIMD -> 2 blocks/CU
void gemm_qkv_ar(const bf16* __restrict__ A, const bf16* __restrict__ B,
                 const float* __restrict__ bias, bf16* __restrict__ C) {
    __shared__ bf16 Bs[2][192 * 64];   // 48 KB total (B only)

    const int tid  = threadIdx.x;
    const int l16  = tid & 15;
    const int quad = (tid >> 4) & 3;
    const int wave = tid >> 6;          // 0..7
    const int wm   = wave >> 2;         // 0..1  (M split, 64 rows each)
    const int wn   = wave & 3;          // 0..3  (N split, 48 cols each)
    const int hh   = l16 & 7;

    // XCD-aware swizzle: grid = 1024 = 64 Mtiles x 16 Ntiles; 1024 % 8 == 0.
    const int bid = (int)blockIdx.x;
    const int seq = (bid & 7) * 128 + (bid >> 3);
    const int tileM = (seq >> 4) * 128;
    const int tileN = (seq & 15) * 192;

    f32x4  acc[4][3] = {};
    bf16x8 aF[2][4], bFA[2][2], bFB[2];

    // per-mt A row base for this lane (row = tileM + wm*64 + mt*16 + l16,
    // k-base = quad*8); in-loop offsets kt + ks*32 elems <= 1984 elems -> imm.
    const bf16* aRow[4];
    #pragma unroll
    for (int mt = 0; mt < 4; ++mt)
        aRow[mt] = A + (size_t)(tileM + wm * 64 + mt * 16 + l16) * KDIM + (quad << 3);

    // prologue: stage B(0), load A(0) frags; full drain; barrier.
    STAGE_B3(0, 0);
    LDA_G(0);
    asm volatile("s_waitcnt vmcnt(0)" ::: "memory");
    BAR();

    #pragma unroll 1
    for (int t = 0; t < NT; ++t) {
        const int buf = t & 1;
        const bf16* __restrict__ bs_ = &Bs[buf][0];

        // stage B(t+1) FIRST (max in-flight window across the MFMA cluster);
        // its buffer's last reads (tile t-1) drained at that wave's lgkm0,
        // which precedes its arrival at BAR(t-1).
        if (t + 1 < NT) STAGE_B3(buf ^ 1, (t + 1) * 64);
        LDBA();
        LDBB();
        WAIT_LGKM0();
        __builtin_amdgcn_s_setprio(1);
        MFMA_N01();
        MFMA_N2();
        __builtin_amdgcn_s_setprio(0);
        // A(t+1) after last aF use (register WAR via program order)
        if (t + 1 < NT) LDA_G((t + 1) * 64);
        asm volatile("s_waitcnt vmcnt(0)" ::: "memory");
        BAR();
    }

    // epilogue: C/D layout col = lane&15, row = quad*4 + reg  [m89/m91-verified]
    float  bvs[3];
    size_t cbase[3];   // h,s,d-dependent part of the scatter address
    #pragma unroll
    for (int an = 0; an < 3; ++an) {
        const int cl = tileN + wn * 48 + an * 16 + l16;
        bvs[an] = bias[cl];
        const int s = cl >> 10;
        const int h = (cl >> 6) & (NHEAD - 1);
        const int d = cl & 63;
        cbase[an] = (size_t)(h * 3 + s) * HSLICE + d;
    }
    #pragma unroll
    for (int mt = 0; mt < 4; ++mt) {
        #pragma unroll
        for (int r = 0; r < 4; ++r) {
            const int rowg = tileM + wm * 64 + mt * 16 + quad * 4 + r;
            const int b  = rowg >> 11;
            const int tt = rowg & (SEQ - 1);
            const size_t rb = (size_t)b * (NHEAD * 3) * HSLICE + (size_t)tt * HDIM;
            #pragma unroll
            for (int an = 0; an < 3; ++an)
                C[rb + cbase[an]] = __float2bfloat16(acc[mt][an][r] + bvs[an]);
        }
    }
}

// ---------------------------------------------------------------------------
// gemm_proj: r13 template at BM=128 BN=128, fp32 row-major out (r14, verified).
// ---------------------------------------------------------------------------

#define STAGE_AP(buf_, kt_) do {                                                \
    _Pragma("unroll")                                                           \
    for (int i_ = 0; i_ < 2; ++i_) {                                            \
        const int c_   = i_ * 512 + tid;                                        \
        const int row_ = c_ >> 3;                                               \
        const int kg_  = (c_ & 7) ^ (row_ & 7);                                 \
        async_copy16(A + (size_t)(tileM + row_) * KDIM + (kt_) + kg_ * 8,       \
                     (char*)Ap[buf_] + c_ * 16);                                \
    } } while (0)

#define STAGE_BP(buf_, kt_) do {                                                \
    _Pragma("unroll")                                                           \
    for (int i_ = 0; i_ < 2; ++i_) {                                            \
        const int c_   = i_ * 512 + tid;                                        \
        const int row_ = c_ >> 3;                                               \
        const int kg_  = (c_ & 7) ^ (row_ & 7);                                 \
        async_copy16(B + (size_t)(tileN + row_) * KDIM + (kt_) + kg_ * 8,       \
                     (char*)Bp[buf_] + c_ * 16);                                \
    } } while (0)

#define LDAP() do {                                                             \
    _Pragma("unroll")                                                           \
    for (int ks_ = 0; ks_ < 2; ++ks_)                                           \
    _Pragma("unroll")                                                           \
    for (int mt_ = 0; mt_ < 4; ++mt_)                                           \
        aF[ks_][mt_] = *(const bf16x8*)(as_ +                                   \
            (size_t)(wm * 64 + mt_ * 16 + l16) * 64 +                           \
            ((((ks_ << 2) | quad) ^ hh) << 3));                                 \
} while (0)

#define LDBP(reg_, nt_) do {                                                    \
    _Pragma("unroll")                                                           \
    for (int ks_ = 0; ks_ < 2; ++ks_)                                           \
        reg_[ks_] = *(const bf16x8*)(bs_ +                                      \
            (size_t)(wn * 32 + (nt_) * 16 + l16) * 64 +                         \
            ((((ks_ << 2) | quad) ^ hh) << 3));                                 \
} while (0)

#define MFMA_P(nt_, reg_) do {                                                  \
    _Pragma("unroll")                                                           \
    for (int ks_ = 0; ks_ < 2; ++ks_)                                           \
    _Pragma("unroll")                                                           \
    for (int mt_ = 0; mt_ < 4; ++mt_)                                           \
        acc[mt_][nt_] = __builtin_amdgcn_mfma_f32_16x16x32_bf16(                \
            aF[ks_][mt_], reg_[ks_], acc[mt_][nt_], 0, 0, 0);                   \
} while (0)

__global__ __launch_bounds__(512, 4)   // 4 waves/SIMD -> 2 blocks/CU
void gemm_proj_2b(const bf16* __restrict__ A, const bf16* __restrict__ B,
                  const float* __restrict__ bias, float* __restrict__ C) {
    __shared__ bf16 Ap[2][128 * 64];   // 32 KB
    __shared__ bf16 Bp[2][128 * 64];   // 32 KB  (64 KB total -> 2 blocks/CU)

    const int tid  = threadIdx.x;
    const int l16  = tid & 15;
    const int quad = (tid >> 4) & 3;
    const int wave = tid >> 6;          // 0..7
    const int wm   = wave >> 2;         // 0..1  (M split, 64 rows each)
    const int wn   = wave & 3;          // 0..3  (N split, 32 cols each)
    const int hh   = l16 & 7;

    // XCD-aware swizzle: grid = 512 = 64 Mtiles x 8 Ntiles; 512 % 8 == 0.
    const int bid = (int)blockIdx.x;
    const int seq = (bid & 7) * 64 + (bid >> 3);
    const int tileM = (seq >> 3) * 128;
    const int tileN = (seq & 7) * 128;

    f32x4  acc[4][2] = {};
    bf16x8 aF[2][4], bF0[2], bF1[2];

    // prologue: A(0),B(0),A(1) = 6 units; tile0 = first 4 -> vmcnt(2)
    STAGE_AP(0, 0);  STAGE_BP(0, 0);  STAGE_AP(1, 64);
    asm volatile("s_waitcnt vmcnt(2)" ::: "memory");
    BAR();

    #pragma unroll 1
    for (int t = 0; t < NT; ++t) {
        const int buf = t & 1;
        const bf16* __restrict__ as_ = &Ap[buf][0];
        const bf16* __restrict__ bs_ = &Bp[buf][0];

        // ---- P1: 10 ds_read_b128; stage B(t+1) (region last read P2(t-1)) ----
        LDAP();
        LDBP(bF0, 0);
        if (t + 1 < NT) STAGE_BP(buf ^ 1, (t + 1) * 64);
        asm volatile("s_waitcnt lgkmcnt(8)");   // hint (10 issued)
        BAR();
        WAIT_LGKM0();
        __builtin_amdgcn_s_setprio(1);
        MFMA_P(0, bF0);
        __builtin_amdgcn_s_setprio(0);
        BAR();

        // ---- P2: 2 ds_read_b128; stage A(t+2) (A(t) reads done @P1) ----
        LDBP(bF1, 1);
        if (t + 2 < NT) STAGE_AP(buf, (t + 2) * 64);
        BAR();
        WAIT_LGKM0();
        __builtin_amdgcn_s_setprio(1);
        MFMA_P(1, bF1);
        __builtin_amdgcn_s_setprio(0);
        // counted drain: keep A(t+2) in flight; tail drains fully at t=NT-2
        if (t + 2 < NT)         asm volatile("s_waitcnt vmcnt(2)" ::: "memory");
        else if (t + 1 < NT)    asm volatile("s_waitcnt vmcnt(0)" ::: "memory");
        BAR();
    }

    // epilogue: fp32 row-major; both nt written temporally adjacent (128B/row WC)
    float bvs[2];
    #pragma unroll
    for (int nt = 0; nt < 2; ++nt) bvs[nt] = bias[tileN + wn * 32 + nt * 16 + l16];
    #pragma unroll
    for (int mt = 0; mt < 4; ++mt) {
        #pragma unroll
        for (int r = 0; r < 4; ++r) {
            const int rowg = tileM + wm * 64 + mt * 16 + quad * 4 + r;
            float* cp = C + (size_t)rowg * DIM + tileN + wn * 32 + l16;
            cp[0]  = acc[mt][0][r] + bvs[0];
            cp[16] = acc[mt][1][r] + bvs[1];
        }
    }
}

// ---- 8 bf16 (as uint4) -> 8 floats
__device__ __forceinline__ void bf8_to_f32(const uint4 u, float* f) {
    union { uint32_t u; float f; } c;
    c.u = u.x << 16;         f[0] = c.f;
    c.u = u.x & 0xffff0000u; f[1] = c.f;
    c.u = u.y << 16;         f[2] = c.f;
    c.u = u.y & 0xffff0000u; f[3] = c.f;
    c.u = u.z << 16;         f[4] = c.f;
    c.u = u.z & 0xffff0000u; f[5] = c.f;
    c.u = u.w << 16;         f[6] = c.f;
    c.u = u.w & 0xffff0000u; f[7] = c.f;
}

// Banded attention v4 over [b,h,s,t,d] qkv: 4 threads/query (16 dims each).
__global__ __launch_bounds__(256)
void attn_banded4(const bf16* __restrict__ qkv, bf16* __restrict__ aout) {
    const int tid = threadIdx.x;
    const int qi  = tid >> 2;          // 0..63
    const int ch  = tid & 3;           // 16-dim chunk
    const int t   = blockIdx.x * 64 + qi;
    const int h   = blockIdx.y;
    const int b   = blockIdx.z;

    const size_t bh3 = (size_t)(b * NHEAD + h) * 3;
    const bf16* qb = qkv + (bh3 + 0) * HSLICE + (size_t)t * HDIM + ch * 16;
    const bf16* kb = qkv + (bh3 + 1) * HSLICE + ch * 16;
    const bf16* vb = qkv + (bh3 + 2) * HSLICE + ch * 16;
    const float scale = 0.125f;        // hd^-0.5

    float q16[16];
    {
        const uint4* qp = (const uint4*)qb;
        uint4 u0 = qp[0], u1 = qp[1];
        bf8_to_f32(u0, q16); bf8_to_f32(u1, q16 + 8);
    }

    float sc[2 * RADIUS + 1];
    #pragma unroll
    for (int j = 0; j < 2 * RADIUS + 1; ++j) {
        const int k = t - RADIUS + j;
        const bool valid = (k >= 0) && (k < SEQ);
        const int kc = valid ? k : t;
        const uint4* kp = (const uint4*)(kb + (size_t)kc * HDIM);
        float kf[16];
        uint4 u0 = kp[0], u1 = kp[1];
        bf8_to_f32(u0, kf); bf8_to_f32(u1, kf + 8);
        float p = 0.f;
        #pragma unroll
        for (int e = 0; e < 16; ++e) p = fmaf(q16[e], kf[e], p);
        p += __shfl_xor(p, 1, 64);     // merge 4 chunks
        p += __shfl_xor(p, 2, 64);
        sc[j] = valid ? p * scale : -1e30f;
    }

    float mx = sc[0];
    #pragma unroll
    for (int j = 1; j < 2 * RADIUS + 1; ++j) mx = fmaxf(mx, sc[j]);
    float sum = 0.f;
    #pragma unroll
    for (int j = 0; j < 2 * RADIUS + 1; ++j) { sc[j] = __expf(sc[j] - mx); sum += sc[j]; }
    const float inv = 1.0f / sum;

    float o16[16];
    #pragma unroll
    for (int e = 0; e < 16; ++e) o16[e] = 0.f;
    #pragma unroll
    for (int j = 0; j < 2 * RADIUS + 1; ++j) {
        const int k = t - RADIUS + j;
        const int kc = (k >= 0 && k < SEQ) ? k : t;   // weight ~0 when clamped
        const uint4* vp = (const uint4*)(vb + (size_t)kc * HDIM);
        float vf[16];
        uint4 u0 = vp[0], u1 = vp[1];
        bf8_to_f32(u0, vf); bf8_to_f32(u1, vf + 8);
        const float w = sc[j];
        #pragma unroll
        for (int e = 0; e < 16; ++e) o16[e] = fmaf(w, vf[e], o16[e]);
    }

    bf16* op = aout + ((size_t)b * SEQ + t) * DIM + h * HDIM + ch * 16;
    #pragma unroll
    for (int c2 = 0; c2 < 2; ++c2) {
        union { u16x8 v; __hip_bfloat16 hh[8]; } o;
        #pragma unroll
        for (int e = 0; e < 8; ++e) o.hh[e] = __float2bfloat16(o16[c2 * 8 + e] * inv);
        ((u16x8*)op)[c2] = o.v;
    }
}

extern "C" void kernel_launch(void* const* d_in, const int* in_sizes, int n_in,
                              void* d_out, int out_size, void* d_ws, size_t ws_size,
                              hipStream_t stream) {
    const float* x      = (const float*)d_in[0];
    const float* w_qkv  = (const float*)d_in[1];
    const float* b_qkv  = (const float*)d_in[2];
    const float* w_proj = (const float*)d_in[3];
    const float* b_proj = (const float*)d_in[4];
    float* out = (float*)d_out;

    bf16* xb     = (bf16*)d_ws;
    bf16* wqkvb  = xb + (size_t)ROWS * DIM;
    bf16* wprojb = wqkvb + (size_t)3072 * 1024;
    bf16* qkvb   = wprojb + (size_t)1024 * 1024;   // [b,h,s,t,d], 48 MiB
    bf16* attnb  = qkvb + (size_t)ROWS * 3072;

    const int n1 = ROWS * DIM / 8, n2 = 3072 * 1024 / 8, n3 = 1024 * 1024 / 8;
    cvt_all<<<(n1 + n2 + n3 + 255) / 256, 256, 0, stream>>>(x, xb, n1, w_qkv, wqkvb, n2,
                                                            w_proj, wprojb, n3);

    // GEMM1: A-in-registers 128x192, 1024 blocks (64 Mtiles x 16 Ntiles), 2 blocks/CU
    gemm_qkv_ar<<<dim3(1024), 512, 0, stream>>>(xb, wqkvb, b_qkv, qkvb);

    // attn v4: 4 threads/query, 32 waves/CU
    attn_banded4<<<dim3(SEQ / 64, NHEAD, BATCH), 256, 0, stream>>>(qkvb, attnb);

    // GEMM2: 2-phase 128x128, 512 blocks (64 Mtiles x 8 Ntiles), 2 blocks/CU
    gemm_proj_2b<<<dim3(512), 512, 0, stream>>>(attnb, wprojb, b_proj, out);
}

// Round 10
// 187.272 us; speedup vs baseline: 1.4591x; 1.4591x over previous
//
#include <hip/hip_runtime.h>
#include <hip/hip_bf16.h>
#include <cstdint>
#include <cstddef>
#include <type_traits>

// FocalAttention: B=4 T=2048 D=1024 H=16 hd=64 RADIUS=4 (banded, 9-wide window)
// fp32 in/out. cvt(fp32->bf16) -> gemm_qkv (2-phase 128x192, 2 blocks/CU) ->
// banded attn (4 threads/query) -> gemm_proj (2-phase 128x128, 2 blocks/CU).
// r8: sched_barrier(0) everywhere = m141 regression. r9: exact-round grids.
// r13/r14: 2-phase+counted-vmcnt+2 blocks/CU, verified 187.1us total.
// r15 LESSON: MFMA fragments must come from LDS banks, never strided global.
// r16/r17 LESSON: full lgkmcnt removal failed the container 2/2 (never ran) —
//   abandoned; do not resubmit that source.
// r18 (this round): round-6 verified source + minimal latency-hiding edit:
//   (1) P1 reads issued ks-interleaved (aF[0],bF[0],aF[1],bF[1]) so the ks=0
//       MFMA cluster depends only on the first 6 (qkv) / 5 (proj) reads;
//   (2) post-BAR drain relaxed lgkmcnt(0) -> lgkmcnt(6) (qkv) / (5) (proj);
//       ks=1 operands are covered by compiler dep-waits (compiler-generated
//       loads, sound tracking). WAR invariant intact: all P1 reads are consumed
//       by MFMAs before the region-end BAR. All waits monotone -> no hang.

typedef __hip_bfloat16 bf16;
typedef __attribute__((ext_vector_type(8))) short bf16x8;   // A/B frag: 8 bf16 = 4 VGPRs
typedef __attribute__((ext_vector_type(4))) float f32x4;    // C/D frag
typedef __attribute__((ext_vector_type(8))) unsigned short u16x8;

#define BATCH  4
#define SEQ    2048
#define DIM    1024
#define NHEAD  16
#define HDIM   64
#define RADIUS 4
#define ROWS   (BATCH * SEQ)          // 8192
#define KDIM   1024
#define NT     (KDIM / 64)            // 16 K-tiles
#define HSLICE (SEQ * HDIM)           // elems per (b,h,s) slice

__device__ __forceinline__ void async_copy16(const void* gptr, void* lptr) {
    __builtin_amdgcn_global_load_lds(
        (const __attribute__((address_space(1))) unsigned int*)(uintptr_t)gptr,
        (__attribute__((address_space(3))) unsigned int*)(uint32_t)(uintptr_t)lptr,
        16, 0, 0);
}

// Fused fp32 -> bf16 convert for all three tensors, 8 elems/thread.
__global__ __launch_bounds__(256)
void cvt_all(const float* __restrict__ s1, bf16* __restrict__ d1, int n1,
             const float* __restrict__ s2, bf16* __restrict__ d2, int n2,
             const float* __restrict__ s3, bf16* __restrict__ d3, int n3) {
    int i = blockIdx.x * blockDim.x + threadIdx.x;
    const float* src; bf16* dst;
    if (i < n1)              { src = s1; dst = d1; }
    else if (i < n1 + n2)    { i -= n1; src = s2; dst = d2; }
    else if (i < n1+n2+n3)   { i -= n1 + n2; src = s3; dst = d3; }
    else return;
    const float4 a = ((const float4*)src)[2 * i];
    const float4 b = ((const float4*)src)[2 * i + 1];
    union { u16x8 v; __hip_bfloat16 h[8]; } o;
    o.h[0] = __float2bfloat16(a.x); o.h[1] = __float2bfloat16(a.y);
    o.h[2] = __float2bfloat16(a.z); o.h[3] = __float2bfloat16(a.w);
    o.h[4] = __float2bfloat16(b.x); o.h[5] = __float2bfloat16(b.y);
    o.h[6] = __float2bfloat16(b.z); o.h[7] = __float2bfloat16(b.w);
    ((u16x8*)dst)[i] = o.v;
}

#define BAR() __builtin_amdgcn_s_barrier()

// ---------------------------------------------------------------------------
// gemm_qkv: 2-phase 128x192 tile, 2 blocks/CU (r13 structure).
// ---------------------------------------------------------------------------

#define STAGE_A2(buf_, kt_) do {                                                \
    _Pragma("unroll")                                                           \
    for (int i_ = 0; i_ < 2; ++i_) {                                            \
        const int c_   = i_ * 512 + tid;                                        \
        const int row_ = c_ >> 3;                                               \
        const int kg_  = (c_ & 7) ^ (row_ & 7);                                 \
        async_copy16(A + (size_t)(tileM + row_) * KDIM + (kt_) + kg_ * 8,       \
                     (char*)As[buf_] + c_ * 16);                                \
    } } while (0)

#define STAGE_B3(buf_, kt_) do {                                                \
    _Pragma("unroll")                                                           \
    for (int j_ = 0; j_ < 3; ++j_) {                                            \
        const int c_   = j_ * 512 + tid;                                        \
        const int row_ = c_ >> 3;                                               \
        const int kg_  = (c_ & 7) ^ (row_ & 7);                                 \
        async_copy16(B + (size_t)(tileN + row_) * KDIM + (kt_) + kg_ * 8,       \
                     (char*)Bs[buf_] + c_ * 16);                                \
    } } while (0)

// ks-sliced fragment loads (issue order ks0-A, ks0-B, ks1-A, ks1-B)
#define LDA_KS(ks_) do {                                                        \
    _Pragma("unroll")                                                           \
    for (int mt_ = 0; mt_ < 4; ++mt_)                                           \
        aF[ks_][mt_] = *(const bf16x8*)(as_ +                                   \
            (size_t)(wm * 64 + mt_ * 16 + l16) * 64 +                           \
            (((((ks_) << 2) | quad) ^ hh) << 3));                               \
} while (0)

#define LDBA_KS(ks_) do {                                                       \
    _Pragma("unroll")                                                           \
    for (int nt_ = 0; nt_ < 2; ++nt_)                                           \
        bFA[ks_][nt_] = *(const bf16x8*)(bs_ +                                  \
            (size_t)(wn * 48 + nt_ * 16 + l16) * 64 +                           \
            (((((ks_) << 2) | quad) ^ hh) << 3));                               \
} while (0)

#define LDBB() do {                                                             \
    _Pragma("unroll")                                                           \
    for (int ks_ = 0; ks_ < 2; ++ks_)                                           \
        bFB[ks_] = *(const bf16x8*)(bs_ +                                       \
            (size_t)(wn * 48 + 32 + l16) * 64 +                                 \
            ((((ks_ << 2) | quad) ^ hh) << 3));                                 \
} while (0)

#define MFMA_N01() do {                                                         \
    _Pragma("unroll")                                                           \
    for (int ks_ = 0; ks_ < 2; ++ks_)                                           \
    _Pragma("unroll")                                                           \
    for (int mt_ = 0; mt_ < 4; ++mt_)                                           \
    _Pragma("unroll")                                                           \
    for (int nt_ = 0; nt_ < 2; ++nt_)                                           \
        acc[mt_][nt_] = __builtin_amdgcn_mfma_f32_16x16x32_bf16(                \
            aF[ks_][mt_], bFA[ks_][nt_], acc[mt_][nt_], 0, 0, 0);               \
} while (0)

#define MFMA_N2() do {                                                          \
    _Pragma("unroll")                                                           \
    for (int ks_ = 0; ks_ < 2; ++ks_)                                           \
    _Pragma("unroll")                                                           \
    for (int mt_ = 0; mt_ < 4; ++mt_)                                           \
        acc[mt_][2] = __builtin_amdgcn_mfma_f32_16x16x32_bf16(                  \
            aF[ks_][mt_], bFB[ks_], acc[mt_][2], 0, 0, 0);                      \
} while (0)

__global__ __launch_bounds__(512, 4)   // 4 waves/SIMD -> 2 blocks/CU
void gemm_qkv_2b(const bf16* __restrict__ A, const bf16* __restrict__ B,
                 const float* __restrict__ bias, bf16* __restrict__ C) {
    __shared__ bf16 As[2][128 * 64];   // 32 KB
    __shared__ bf16 Bs[2][192 * 64];   // 48 KB  (80 KB total -> 2 blocks/CU)

    const int tid  = threadIdx.x;
    const int l16  = tid & 15;
    const int quad = (tid >> 4) & 3;
    const int wave = tid >> 6;          // 0..7
    const int wm   = wave >> 2;         // 0..1  (M split, 64 rows each)
    const int wn   = wave & 3;          // 0..3  (N split, 48 cols each)
    const int hh   = l16 & 7;

    // XCD-aware swizzle: grid = 1024 = 64 Mtiles x 16 Ntiles; 1024 % 8 == 0.
    const int bid = (int)blockIdx.x;
    const int seq = (bid & 7) * 128 + (bid >> 3);
    const int tileM = (seq >> 4) * 128;
    const int tileN = (seq & 15) * 192;

    f32x4  acc[4][3] = {};
    bf16x8 aF[2][4], bFA[2][2], bFB[2];

    // prologue: A(0),B(0),A(1) = 7 units; tile0 = first 5 -> vmcnt(2)
    STAGE_A2(0, 0);  STAGE_B3(0, 0);  STAGE_A2(1, 64);
    asm volatile("s_waitcnt vmcnt(2)" ::: "memory");
    BAR();

    #pragma unroll 1
    for (int t = 0; t < NT; ++t) {
        const int buf = t & 1;
        const bf16* __restrict__ as_ = &As[buf][0];
        const bf16* __restrict__ bs_ = &Bs[buf][0];

        // ---- P1: 12 ds_read_b128 (ks-interleaved); stage B(t+1) ----
        LDA_KS(0); LDBA_KS(0);     // reads 1-6: ks=0 operands
        LDA_KS(1); LDBA_KS(1);     // reads 7-12: ks=1 operands
        if (t + 1 < NT) STAGE_B3(buf ^ 1, (t + 1) * 64);
        asm volatile("s_waitcnt lgkmcnt(8)");   // stagger hint (12 issued)
        BAR();
        asm volatile("s_waitcnt lgkmcnt(6)");   // ks=0 operands landed
        __builtin_amdgcn_s_setprio(1);
        MFMA_N01();                 // ks=1 cluster guarded by compiler dep-waits
        __builtin_amdgcn_s_setprio(0);
        BAR();

        // ---- P2: 2 ds_read_b128; stage A(t+2) (A(t) reads done in P1) ----
        LDBB();
        if (t + 2 < NT) STAGE_A2(buf, (t + 2) * 64);
        BAR();
        asm volatile("s_waitcnt lgkmcnt(0)");
        __builtin_amdgcn_s_setprio(1);
        MFMA_N2();
        __builtin_amdgcn_s_setprio(0);
        // counted drain: keep A(t+2) in flight; tail drains fully at t=NT-2
        if (t + 2 < NT)         asm volatile("s_waitcnt vmcnt(2)" ::: "memory");
        else if (t + 1 < NT)    asm volatile("s_waitcnt vmcnt(0)" ::: "memory");
        BAR();
    }

    // epilogue: C/D layout col = lane&15, row = quad*4 + reg  [m89/m91-verified]
    float  bvs[3];
    size_t cbase[3];   // h,s,d-dependent part of the scatter address
    #pragma unroll
    for (int an = 0; an < 3; ++an) {
        const int cl = tileN + wn * 48 + an * 16 + l16;
        bvs[an] = bias[cl];
        const int s = cl >> 10;
        const int h = (cl >> 6) & (NHEAD - 1);
        const int d = cl & 63;
        cbase[an] = (size_t)(h * 3 + s) * HSLICE + d;
    }
    #pragma unroll
    for (int mt = 0; mt < 4; ++mt) {
        #pragma unroll
        for (int r = 0; r < 4; ++r) {
            const int rowg = tileM + wm * 64 + mt * 16 + quad * 4 + r;
            const int b  = rowg >> 11;
            const int tt = rowg & (SEQ - 1);
            const size_t rb = (size_t)b * (NHEAD * 3) * HSLICE + (size_t)tt * HDIM;
            #pragma unroll
            for (int an = 0; an < 3; ++an)
                C[rb + cbase[an]] = __float2bfloat16(acc[mt][an][r] + bvs[an]);
        }
    }
}

// ---------------------------------------------------------------------------
// gemm_proj: r13 template at BM=128 BN=128, fp32 row-major out.
// ---------------------------------------------------------------------------

#define STAGE_AP(buf_, kt_) do {                                                \
    _Pragma("unroll")                                                           \
    for (int i_ = 0; i_ < 2; ++i_) {                                            \
        const int c_   = i_ * 512 + tid;                                        \
        const int row_ = c_ >> 3;                                               \
        const int kg_  = (c_ & 7) ^ (row_ & 7);                                 \
        async_copy16(A + (size_t)(tileM + row_) * KDIM + (kt_) + kg_ * 8,       \
                     (char*)Ap[buf_] + c_ * 16);                                \
    } } while (0)

#define STAGE_BP(buf_, kt_) do {                                                \
    _Pragma("unroll")                                                           \
    for (int i_ = 0; i_ < 2; ++i_) {                                            \
        const int c_   = i_ * 512 + tid;                                        \
        const int row_ = c_ >> 3;                                               \
        const int kg_  = (c_ & 7) ^ (row_ & 7);                                 \
        async_copy16(B + (size_t)(tileN + row_) * KDIM + (kt_) + kg_ * 8,       \
                     (char*)Bp[buf_] + c_ * 16);                                \
    } } while (0)

#define LDAP_KS(ks_) do {                                                       \
    _Pragma("unroll")                                                           \
    for (int mt_ = 0; mt_ < 4; ++mt_)                                           \
        aF[ks_][mt_] = *(const bf16x8*)(as_ +                                   \
            (size_t)(wm * 64 + mt_ * 16 + l16) * 64 +                           \
            (((((ks_) << 2) | quad) ^ hh) << 3));                               \
} while (0)

#define LDBP_KS(reg_, nt_, ks_) do {                                            \
        reg_[ks_] = *(const bf16x8*)(bs_ +                                      \
            (size_t)(wn * 32 + (nt_) * 16 + l16) * 64 +                         \
            (((((ks_) << 2) | quad) ^ hh) << 3));                               \
} while (0)

#define MFMA_P(nt_, reg_) do {                                                  \
    _Pragma("unroll")                                                           \
    for (int ks_ = 0; ks_ < 2; ++ks_)                                           \
    _Pragma("unroll")                                                           \
    for (int mt_ = 0; mt_ < 4; ++mt_)                                           \
        acc[mt_][nt_] = __builtin_amdgcn_mfma_f32_16x16x32_bf16(                \
            aF[ks_][mt_], reg_[ks_], acc[mt_][nt_], 0, 0, 0);                   \
} while (0)

__global__ __launch_bounds__(512, 4)   // 4 waves/SIMD -> 2 blocks/CU
void gemm_proj_2b(const bf16* __restrict__ A, const bf16* __restrict__ B,
                  const float* __restrict__ bias, float* __restrict__ C) {
    __shared__ bf16 Ap[2][128 * 64];   // 32 KB
    __shared__ bf16 Bp[2][128 * 64];   // 32 KB  (64 KB total -> 2 blocks/CU)

    const int tid  = threadIdx.x;
    const int l16  = tid & 15;
    const int quad = (tid >> 4) & 3;
    const int wave = tid >> 6;          // 0..7
    const int wm   = wave >> 2;         // 0..1  (M split, 64 rows each)
    const int wn   = wave & 3;          // 0..3  (N split, 32 cols each)
    const int hh   = l16 & 7;

    // XCD-aware swizzle: grid = 512 = 64 Mtiles x 8 Ntiles; 512 % 8 == 0.
    const int bid = (int)blockIdx.x;
    const int seq = (bid & 7) * 64 + (bid >> 3);
    const int tileM = (seq >> 3) * 128;
    const int tileN = (seq & 7) * 128;

    f32x4  acc[4][2] = {};
    bf16x8 aF[2][4], bF0[2], bF1[2];

    // prologue: A(0),B(0),A(1) = 6 units; tile0 = first 4 -> vmcnt(2)
    STAGE_AP(0, 0);  STAGE_BP(0, 0);  STAGE_AP(1, 64);
    asm volatile("s_waitcnt vmcnt(2)" ::: "memory");
    BAR();

    #pragma unroll 1
    for (int t = 0; t < NT; ++t) {
        const int buf = t & 1;
        const bf16* __restrict__ as_ = &Ap[buf][0];
        const bf16* __restrict__ bs_ = &Bp[buf][0];

        // ---- P1: 10 ds_read_b128 (ks-interleaved); stage B(t+1) ----
        LDAP_KS(0); LDBP_KS(bF0, 0, 0);   // reads 1-5: ks=0 operands
        LDAP_KS(1); LDBP_KS(bF0, 0, 1);   // reads 6-10: ks=1 operands
        if (t + 1 < NT) STAGE_BP(buf ^ 1, (t + 1) * 64);
        asm volatile("s_waitcnt lgkmcnt(8)");   // stagger hint (10 issued)
        BAR();
        asm volatile("s_waitcnt lgkmcnt(5)");   // ks=0 operands landed
        __builtin_amdgcn_s_setprio(1);
        MFMA_P(0, bF0);
        __builtin_amdgcn_s_setprio(0);
        BAR();

        // ---- P2: 2 ds_read_b128; stage A(t+2) (A(t) reads done in P1) ----
        LDBP_KS(bF1, 1, 0); LDBP_KS(bF1, 1, 1);
        if (t + 2 < NT) STAGE_AP(buf, (t + 2) * 64);
        BAR();
        asm volatile("s_waitcnt lgkmcnt(0)");
        __builtin_amdgcn_s_setprio(1);
        MFMA_P(1, bF1);
        __builtin_amdgcn_s_setprio(0);
        // counted drain: keep A(t+2) in flight; tail drains fully at t=NT-2
        if (t + 2 < NT)         asm volatile("s_waitcnt vmcnt(2)" ::: "memory");
        else if (t + 1 < NT)    asm volatile("s_waitcnt vmcnt(0)" ::: "memory");
        BAR();
    }

    // epilogue: fp32 row-major; both nt written temporally adjacent (128B/row WC)
    float bvs[2];
    #pragma unroll
    for (int nt = 0; nt < 2; ++nt) bvs[nt] = bias[tileN + wn * 32 + nt * 16 + l16];
    #pragma unroll
    for (int mt = 0; mt < 4; ++mt) {
        #pragma unroll
        for (int r = 0; r < 4; ++r) {
            const int rowg = tileM + wm * 64 + mt * 16 + quad * 4 + r;
            float* cp = C + (size_t)rowg * DIM + tileN + wn * 32 + l16;
            cp[0]  = acc[mt][0][r] + bvs[0];
            cp[16] = acc[mt][1][r] + bvs[1];
        }
    }
}

// ---- 8 bf16 (as uint4) -> 8 floats
__device__ __forceinline__ void bf8_to_f32(const uint4 u, float* f) {
    union { uint32_t u; float f; } c;
    c.u = u.x << 16;         f[0] = c.f;
    c.u = u.x & 0xffff0000u; f[1] = c.f;
    c.u = u.y << 16;         f[2] = c.f;
    c.u = u.y & 0xffff0000u; f[3] = c.f;
    c.u = u.z << 16;         f[4] = c.f;
    c.u = u.z & 0xffff0000u; f[5] = c.f;
    c.u = u.w << 16;         f[6] = c.f;
    c.u = u.w & 0xffff0000u; f[7] = c.f;
}

// Banded attention v4 over [b,h,s,t,d] qkv: 4 threads/query (16 dims each).
__global__ __launch_bounds__(256)
void attn_banded4(const bf16* __restrict__ qkv, bf16* __restrict__ aout) {
    const int tid = threadIdx.x;
    const int qi  = tid >> 2;          // 0..63
    const int ch  = tid & 3;           // 16-dim chunk
    const int t   = blockIdx.x * 64 + qi;
    const int h   = blockIdx.y;
    const int b   = blockIdx.z;

    const size_t bh3 = (size_t)(b * NHEAD + h) * 3;
    const bf16* qb = qkv + (bh3 + 0) * HSLICE + (size_t)t * HDIM + ch * 16;
    const bf16* kb = qkv + (bh3 + 1) * HSLICE + ch * 16;
    const bf16* vb = qkv + (bh3 + 2) * HSLICE + ch * 16;
    const float scale = 0.125f;        // hd^-0.5

    float q16[16];
    {
        const uint4* qp = (const uint4*)qb;
        uint4 u0 = qp[0], u1 = qp[1];
        bf8_to_f32(u0, q16); bf8_to_f32(u1, q16 + 8);
    }

    float sc[2 * RADIUS + 1];
    #pragma unroll
    for (int j = 0; j < 2 * RADIUS + 1; ++j) {
        const int k = t - RADIUS + j;
        const bool valid = (k >= 0) && (k < SEQ);
        const int kc = valid ? k : t;
        const uint4* kp = (const uint4*)(kb + (size_t)kc * HDIM);
        float kf[16];
        uint4 u0 = kp[0], u1 = kp[1];
        bf8_to_f32(u0, kf); bf8_to_f32(u1, kf + 8);
        float p = 0.f;
        #pragma unroll
        for (int e = 0; e < 16; ++e) p = fmaf(q16[e], kf[e], p);
        p += __shfl_xor(p, 1, 64);     // merge 4 chunks
        p += __shfl_xor(p, 2, 64);
        sc[j] = valid ? p * scale : -1e30f;
    }

    float mx = sc[0];
    #pragma unroll
    for (int j = 1; j < 2 * RADIUS + 1; ++j) mx = fmaxf(mx, sc[j]);
    float sum = 0.f;
    #pragma unroll
    for (int j = 0; j < 2 * RADIUS + 1; ++j) { sc[j] = __expf(sc[j] - mx); sum += sc[j]; }
    const float inv = 1.0f / sum;

    float o16[16];
    #pragma unroll
    for (int e = 0; e < 16; ++e) o16[e] = 0.f;
    #pragma unroll
    for (int j = 0; j < 2 * RADIUS + 1; ++j) {
        const int k = t - RADIUS + j;
        const int kc = (k >= 0 && k < SEQ) ? k : t;   // weight ~0 when clamped
        const uint4* vp = (const uint4*)(vb + (size_t)kc * HDIM);
        float vf[16];
        uint4 u0 = vp[0], u1 = vp[1];
        bf8_to_f32(u0, vf); bf8_to_f32(u1, vf + 8);
        const float w = sc[j];
        #pragma unroll
        for (int e = 0; e < 16; ++e) o16[e] = fmaf(w, vf[e], o16[e]);
    }

    bf16* op = aout + ((size_t)b * SEQ + t) * DIM + h * HDIM + ch * 16;
    #pragma unroll
    for (int c2 = 0; c2 < 2; ++c2) {
        union { u16x8 v; __hip_bfloat16 hh[8]; } o;
        #pragma unroll
        for (int e = 0; e < 8; ++e) o.hh[e] = __float2bfloat16(o16[c2 * 8 + e] * inv);
        ((u16x8*)op)[c2] = o.v;
    }
}

extern "C" void kernel_launch(void* const* d_in, const int* in_sizes, int n_in,
                              void* d_out, int out_size, void* d_ws, size_t ws_size,
                              hipStream_t stream) {
    const float* x      = (const float*)d_in[0];
    const float* w_qkv  = (const float*)d_in[1];
    const float* b_qkv  = (const float*)d_in[2];
    const float* w_proj = (const float*)d_in[3];
    const float* b_proj = (const float*)d_in[4];
    float* out = (float*)d_out;

    bf16* xb     = (bf16*)d_ws;
    bf16* wqkvb  = xb + (size_t)ROWS * DIM;
    bf16* wprojb = wqkvb + (size_t)3072 * 1024;
    bf16* qkvb   = wprojb + (size_t)1024 * 1024;   // [b,h,s,t,d], 48 MiB
    bf16* attnb  = qkvb + (size_t)ROWS * 3072;

    const int n1 = ROWS * DIM / 8, n2 = 3072 * 1024 / 8, n3 = 1024 * 1024 / 8;
    cvt_all<<<(n1 + n2 + n3 + 255) / 256, 256, 0, stream>>>(x, xb, n1, w_qkv, wqkvb, n2,
                                                            w_proj, wprojb, n3);

    // GEMM1: 2-phase 128x192, 1024 blocks (64 Mtiles x 16 Ntiles), 2 blocks/CU
    gemm_qkv_2b<<<dim3(1024), 512, 0, stream>>>(xb, wqkvb, b_qkv, qkvb);

    // attn v4: 4 threads/query, 32 waves/CU
    attn_banded4<<<dim3(SEQ / 64, NHEAD, BATCH), 256, 0, stream>>>(qkvb, attnb);

    // GEMM2: 2-phase 128x128, 512 blocks (64 Mtiles x 8 Ntiles), 2 blocks/CU
    gemm_proj_2b<<<dim3(512), 512, 0, stream>>>(attnb, wprojb, b_proj, out);
}

// Round 11
// 184.086 us; speedup vs baseline: 1.4844x; 1.0173x over previous
//
#include <hip/hip_runtime.h>
#include <hip/hip_bf16.h>
#include <cstdint>
#include <cstddef>
#include <type_traits>

// FocalAttention: B=4 T=2048 D=1024 H=16 hd=64 RADIUS=4 (banded, 9-wide window)
// fp32 in/out. cvt(fp32->bf16) -> gemm_qkv (4-wave 128x192, per-wave 64x96) ->
// banded attn (4 threads/query) -> gemm_proj (2-phase 128x128, 2 blocks/CU).
// r8: sched_barrier(0) everywhere = m141 regression. r9: exact-round grids.
// r13/r14: 2-phase+counted-vmcnt+2 blocks/CU, verified 187.1us total.
// r15 LESSON: MFMA fragments must come from LDS banks, never strided global.
// r16/r17: lgkmcnt removal failed container 2/2, abandoned. r18: ks-interleave
//   + relaxed drain = NEUTRAL -> drain wasn't the cost; qkv is LDS+MFMA
//   serial-sum bound (2375+1862 cyc/K-tile/CU ~= 4494 wall).
// r19 (this round): cut LDS READ volume, not the schedule. Reads/wave =
//   (M_w+N_w)*K*2B; FLOP = M_w*N_w*K*2 -> ratio set by per-wave tile ONLY.
//   64x48 (8 waves) -> 64x96 (4 waves): ratio 27->38 FLOP/B; per-CU LDS
//   304->240KB/K-tile (1875 cyc) vs MFMA 1862. Occupancy halves (2 waves/SIMD,
//   VGPR ~196 of 256 budget) — acceptable per serial-sum model.
//   Ledger (256 thr): units A=4,B=6; B(t+1)@P1, A(t+2)@P2; outstanding@P2-end
//   = 4+6+4 = 14 -> vmcnt(4) drains exactly t+1; tail vmcnt(0) @ t=NT-2.

typedef __hip_bfloat16 bf16;
typedef __attribute__((ext_vector_type(8))) short bf16x8;   // A/B frag: 8 bf16 = 4 VGPRs
typedef __attribute__((ext_vector_type(4))) float f32x4;    // C/D frag
typedef __attribute__((ext_vector_type(8))) unsigned short u16x8;

#define BATCH  4
#define SEQ    2048
#define DIM    1024
#define NHEAD  16
#define HDIM   64
#define RADIUS 4
#define ROWS   (BATCH * SEQ)          // 8192
#define KDIM   1024
#define NT     (KDIM / 64)            // 16 K-tiles
#define HSLICE (SEQ * HDIM)           // elems per (b,h,s) slice

__device__ __forceinline__ void async_copy16(const void* gptr, void* lptr) {
    __builtin_amdgcn_global_load_lds(
        (const __attribute__((address_space(1))) unsigned int*)(uintptr_t)gptr,
        (__attribute__((address_space(3))) unsigned int*)(uint32_t)(uintptr_t)lptr,
        16, 0, 0);
}

// Fused fp32 -> bf16 convert for all three tensors, 8 elems/thread.
__global__ __launch_bounds__(256)
void cvt_all(const float* __restrict__ s1, bf16* __restrict__ d1, int n1,
             const float* __restrict__ s2, bf16* __restrict__ d2, int n2,
             const float* __restrict__ s3, bf16* __restrict__ d3, int n3) {
    int i = blockIdx.x * blockDim.x + threadIdx.x;
    const float* src; bf16* dst;
    if (i < n1)              { src = s1; dst = d1; }
    else if (i < n1 + n2)    { i -= n1; src = s2; dst = d2; }
    else if (i < n1+n2+n3)   { i -= n1 + n2; src = s3; dst = d3; }
    else return;
    const float4 a = ((const float4*)src)[2 * i];
    const float4 b = ((const float4*)src)[2 * i + 1];
    union { u16x8 v; __hip_bfloat16 h[8]; } o;
    o.h[0] = __float2bfloat16(a.x); o.h[1] = __float2bfloat16(a.y);
    o.h[2] = __float2bfloat16(a.z); o.h[3] = __float2bfloat16(a.w);
    o.h[4] = __float2bfloat16(b.x); o.h[5] = __float2bfloat16(b.y);
    o.h[6] = __float2bfloat16(b.z); o.h[7] = __float2bfloat16(b.w);
    ((u16x8*)dst)[i] = o.v;
}

#define BAR() __builtin_amdgcn_s_barrier()

// ---------------------------------------------------------------------------
// gemm_qkv: 4-wave 128x192 tile, per-wave 64x96, 2 blocks/CU.
// ---------------------------------------------------------------------------

// A tile = 128x64 = 16 KB = 4 units of 256 thr x 16 B.
#define STAGE_A4(buf_, kt_) do {                                                \
    _Pragma("unroll")                                                           \
    for (int i_ = 0; i_ < 4; ++i_) {                                            \
        const int c_   = i_ * 256 + tid;                                        \
        const int row_ = c_ >> 3;                                               \
        const int kg_  = (c_ & 7) ^ (row_ & 7);                                 \
        async_copy16(A + (size_t)(tileM + row_) * KDIM + (kt_) + kg_ * 8,       \
                     (char*)As[buf_] + c_ * 16);                                \
    } } while (0)

// B tile = 192x64 = 24 KB = 6 units of 256 thr x 16 B.
#define STAGE_B6(buf_, kt_) do {                                                \
    _Pragma("unroll")                                                           \
    for (int j_ = 0; j_ < 6; ++j_) {                                            \
        const int c_   = j_ * 256 + tid;                                        \
        const int row_ = c_ >> 3;                                               \
        const int kg_  = (c_ & 7) ^ (row_ & 7);                                 \
        async_copy16(B + (size_t)(tileN + row_) * KDIM + (kt_) + kg_ * 8,       \
                     (char*)Bs[buf_] + c_ * 16);                                \
    } } while (0)

#define LDA8() do {                                                             \
    _Pragma("unroll")                                                           \
    for (int ks_ = 0; ks_ < 2; ++ks_)                                           \
    _Pragma("unroll")                                                           \
    for (int mt_ = 0; mt_ < 4; ++mt_)                                           \
        aF[ks_][mt_] = *(const bf16x8*)(as_ +                                   \
            (size_t)(wm * 64 + mt_ * 16 + l16) * 64 +                           \
            ((((ks_ << 2) | quad) ^ hh) << 3));                                 \
} while (0)

// bFA: nt 0..3 (8 reads). bFB: nt 4..5 (4 reads).  row = wn*96 + ...
#define LDBA() do {                                                             \
    _Pragma("unroll")                                                           \
    for (int ks_ = 0; ks_ < 2; ++ks_)                                           \
    _Pragma("unroll")                                                           \
    for (int nt_ = 0; nt_ < 4; ++nt_)                                           \
        bFA[ks_][nt_] = *(const bf16x8*)(bs_ +                                  \
            (size_t)(wn * 96 + nt_ * 16 + l16) * 64 +                           \
            ((((ks_ << 2) | quad) ^ hh) << 3));                                 \
} while (0)

#define LDBB() do {                                                             \
    _Pragma("unroll")                                                           \
    for (int ks_ = 0; ks_ < 2; ++ks_)                                           \
    _Pragma("unroll")                                                           \
    for (int j_ = 0; j_ < 2; ++j_)                                              \
        bFB[ks_][j_] = *(const bf16x8*)(bs_ +                                   \
            (size_t)(wn * 96 + 64 + j_ * 16 + l16) * 64 +                       \
            ((((ks_ << 2) | quad) ^ hh) << 3));                                 \
} while (0)

// P1 cluster: 4mt x 4nt x 2ks = 32 MFMA.
#define MFMA_P1() do {                                                          \
    _Pragma("unroll")                                                           \
    for (int ks_ = 0; ks_ < 2; ++ks_)                                           \
    _Pragma("unroll")                                                           \
    for (int mt_ = 0; mt_ < 4; ++mt_)                                           \
    _Pragma("unroll")                                                           \
    for (int nt_ = 0; nt_ < 4; ++nt_)                                           \
        acc[mt_][nt_] = __builtin_amdgcn_mfma_f32_16x16x32_bf16(                \
            aF[ks_][mt_], bFA[ks_][nt_], acc[mt_][nt_], 0, 0, 0);               \
} while (0)

// P2 cluster: 4mt x 2nt x 2ks = 16 MFMA (acc cols 4,5).
#define MFMA_P2() do {                                                          \
    _Pragma("unroll")                                                           \
    for (int ks_ = 0; ks_ < 2; ++ks_)                                           \
    _Pragma("unroll")                                                           \
    for (int mt_ = 0; mt_ < 4; ++mt_)                                           \
    _Pragma("unroll")                                                           \
    for (int j_ = 0; j_ < 2; ++j_)                                              \
        acc[mt_][4 + j_] = __builtin_amdgcn_mfma_f32_16x16x32_bf16(             \
            aF[ks_][mt_], bFB[ks_][j_], acc[mt_][4 + j_], 0, 0, 0);             \
} while (0)

__global__ __launch_bounds__(256, 2)   // 2 waves/SIMD -> 2 blocks/CU, VGPR cap 256
void gemm_qkv_4w(const bf16* __restrict__ A, const bf16* __restrict__ B,
                 const float* __restrict__ bias, bf16* __restrict__ C) {
    __shared__ bf16 As[2][128 * 64];   // 32 KB
    __shared__ bf16 Bs[2][192 * 64];   // 48 KB  (80 KB total -> 2 blocks/CU)

    const int tid  = threadIdx.x;
    const int l16  = tid & 15;
    const int quad = (tid >> 4) & 3;
    const int wave = tid >> 6;          // 0..3
    const int wm   = wave >> 1;         // 0..1  (M split, 64 rows each)
    const int wn   = wave & 1;          // 0..1  (N split, 96 cols each)
    const int hh   = l16 & 7;

    // XCD-aware swizzle: grid = 1024 = 64 Mtiles x 16 Ntiles; 1024 % 8 == 0.
    const int bid = (int)blockIdx.x;
    const int seq = (bid & 7) * 128 + (bid >> 3);
    const int tileM = (seq >> 4) * 128;
    const int tileN = (seq & 15) * 192;

    f32x4  acc[4][6] = {};              // 96 VGPR accumulator (per-wave 64x96)
    bf16x8 aF[2][4], bFA[2][4], bFB[2][2];

    // prologue: A(0),B(0),A(1) = 14 units; tile0 = first 10 -> vmcnt(4)
    STAGE_A4(0, 0);  STAGE_B6(0, 0);  STAGE_A4(1, 64);
    asm volatile("s_waitcnt vmcnt(4)" ::: "memory");
    BAR();

    #pragma unroll 1
    for (int t = 0; t < NT; ++t) {
        const int buf = t & 1;
        const bf16* __restrict__ as_ = &As[buf][0];
        const bf16* __restrict__ bs_ = &Bs[buf][0];

        // ---- P1: 16 ds_read_b128; stage B(t+1) (region last read P2(t-1)) ----
        LDA8();
        LDBA();
        if (t + 1 < NT) STAGE_B6(buf ^ 1, (t + 1) * 64);
        asm volatile("s_waitcnt lgkmcnt(8)");   // stagger hint (16 issued)
        BAR();
        asm volatile("s_waitcnt lgkmcnt(0)");
        __builtin_amdgcn_s_setprio(1);
        MFMA_P1();
        __builtin_amdgcn_s_setprio(0);
        BAR();

        // ---- P2: 4 ds_read_b128; stage A(t+2) (A(t) reads done in P1) ----
        LDBB();
        if (t + 2 < NT) STAGE_A4(buf, (t + 2) * 64);
        BAR();
        asm volatile("s_waitcnt lgkmcnt(0)");
        __builtin_amdgcn_s_setprio(1);
        MFMA_P2();
        __builtin_amdgcn_s_setprio(0);
        // counted drain: keep A(t+2) in flight; tail drains fully at t=NT-2
        if (t + 2 < NT)         asm volatile("s_waitcnt vmcnt(4)" ::: "memory");
        else if (t + 1 < NT)    asm volatile("s_waitcnt vmcnt(0)" ::: "memory");
        BAR();
    }

    // epilogue: C/D layout col = lane&15, row = quad*4 + reg  [m89/m91-verified]
    float  bvs[6];
    size_t cbase[6];   // h,s,d-dependent part of the scatter address
    #pragma unroll
    for (int an = 0; an < 6; ++an) {
        const int cl = tileN + wn * 96 + an * 16 + l16;
        bvs[an] = bias[cl];
        const int s = cl >> 10;
        const int h = (cl >> 6) & (NHEAD - 1);
        const int d = cl & 63;
        cbase[an] = (size_t)(h * 3 + s) * HSLICE + d;
    }
    #pragma unroll
    for (int mt = 0; mt < 4; ++mt) {
        #pragma unroll
        for (int r = 0; r < 4; ++r) {
            const int rowg = tileM + wm * 64 + mt * 16 + quad * 4 + r;
            const int b  = rowg >> 11;
            const int tt = rowg & (SEQ - 1);
            const size_t rb = (size_t)b * (NHEAD * 3) * HSLICE + (size_t)tt * HDIM;
            #pragma unroll
            for (int an = 0; an < 6; ++an)
                C[rb + cbase[an]] = __float2bfloat16(acc[mt][an][r] + bvs[an]);
        }
    }
}

// ---------------------------------------------------------------------------
// gemm_proj: r13 template at BM=128 BN=128, fp32 row-major out (round-10
// verified source, unchanged).
// ---------------------------------------------------------------------------

#define STAGE_AP(buf_, kt_) do {                                                \
    _Pragma("unroll")                                                           \
    for (int i_ = 0; i_ < 2; ++i_) {                                            \
        const int c_   = i_ * 512 + tid;                                        \
        const int row_ = c_ >> 3;                                               \
        const int kg_  = (c_ & 7) ^ (row_ & 7);                                 \
        async_copy16(A + (size_t)(tileM + row_) * KDIM + (kt_) + kg_ * 8,       \
                     (char*)Ap[buf_] + c_ * 16);                                \
    } } while (0)

#define STAGE_BP(buf_, kt_) do {                                                \
    _Pragma("unroll")                                                           \
    for (int i_ = 0; i_ < 2; ++i_) {                                            \
        const int c_   = i_ * 512 + tid;                                        \
        const int row_ = c_ >> 3;                                               \
        const int kg_  = (c_ & 7) ^ (row_ & 7);                                 \
        async_copy16(B + (size_t)(tileN + row_) * KDIM + (kt_) + kg_ * 8,       \
                     (char*)Bp[buf_] + c_ * 16);                                \
    } } while (0)

#define LDAP_KS(ks_) do {                                                       \
    _Pragma("unroll")                                                           \
    for (int mt_ = 0; mt_ < 4; ++mt_)                                           \
        aF[ks_][mt_] = *(const bf16x8*)(as_ +                                   \
            (size_t)(wm * 64 + mt_ * 16 + l16) * 64 +                           \
            (((((ks_) << 2) | quad) ^ hh) << 3));                               \
} while (0)

#define LDBP_KS(reg_, nt_, ks_) do {                                            \
        reg_[ks_] = *(const bf16x8*)(bs_ +                                      \
            (size_t)(wn * 32 + (nt_) * 16 + l16) * 64 +                         \
            (((((ks_) << 2) | quad) ^ hh) << 3));                               \
} while (0)

#define MFMA_P(nt_, reg_) do {                                                  \
    _Pragma("unroll")                                                           \
    for (int ks_ = 0; ks_ < 2; ++ks_)                                           \
    _Pragma("unroll")                                                           \
    for (int mt_ = 0; mt_ < 4; ++mt_)                                           \
        acc[mt_][nt_] = __builtin_amdgcn_mfma_f32_16x16x32_bf16(                \
            aF[ks_][mt_], reg_[ks_], acc[mt_][nt_], 0, 0, 0);                   \
} while (0)

__global__ __launch_bounds__(512, 4)   // 4 waves/SIMD -> 2 blocks/CU
void gemm_proj_2b(const bf16* __restrict__ A, const bf16* __restrict__ B,
                  const float* __restrict__ bias, float* __restrict__ C) {
    __shared__ bf16 Ap[2][128 * 64];   // 32 KB
    __shared__ bf16 Bp[2][128 * 64];   // 32 KB  (64 KB total -> 2 blocks/CU)

    const int tid  = threadIdx.x;
    const int l16  = tid & 15;
    const int quad = (tid >> 4) & 3;
    const int wave = tid >> 6;          // 0..7
    const int wm   = wave >> 2;         // 0..1  (M split, 64 rows each)
    const int wn   = wave & 3;          // 0..3  (N split, 32 cols each)
    const int hh   = l16 & 7;

    // XCD-aware swizzle: grid = 512 = 64 Mtiles x 8 Ntiles; 512 % 8 == 0.
    const int bid = (int)blockIdx.x;
    const int seq = (bid & 7) * 64 + (bid >> 3);
    const int tileM = (seq >> 3) * 128;
    const int tileN = (seq & 7) * 128;

    f32x4  acc[4][2] = {};
    bf16x8 aF[2][4], bF0[2], bF1[2];

    // prologue: A(0),B(0),A(1) = 6 units; tile0 = first 4 -> vmcnt(2)
    STAGE_AP(0, 0);  STAGE_BP(0, 0);  STAGE_AP(1, 64);
    asm volatile("s_waitcnt vmcnt(2)" ::: "memory");
    BAR();

    #pragma unroll 1
    for (int t = 0; t < NT; ++t) {
        const int buf = t & 1;
        const bf16* __restrict__ as_ = &Ap[buf][0];
        const bf16* __restrict__ bs_ = &Bp[buf][0];

        // ---- P1: 10 ds_read_b128 (ks-interleaved); stage B(t+1) ----
        LDAP_KS(0); LDBP_KS(bF0, 0, 0);   // reads 1-5: ks=0 operands
        LDAP_KS(1); LDBP_KS(bF0, 0, 1);   // reads 6-10: ks=1 operands
        if (t + 1 < NT) STAGE_BP(buf ^ 1, (t + 1) * 64);
        asm volatile("s_waitcnt lgkmcnt(8)");   // stagger hint (10 issued)
        BAR();
        asm volatile("s_waitcnt lgkmcnt(5)");   // ks=0 operands landed
        __builtin_amdgcn_s_setprio(1);
        MFMA_P(0, bF0);
        __builtin_amdgcn_s_setprio(0);
        BAR();

        // ---- P2: 2 ds_read_b128; stage A(t+2) (A(t) reads done in P1) ----
        LDBP_KS(bF1, 1, 0); LDBP_KS(bF1, 1, 1);
        if (t + 2 < NT) STAGE_AP(buf, (t + 2) * 64);
        BAR();
        asm volatile("s_waitcnt lgkmcnt(0)");
        __builtin_amdgcn_s_setprio(1);
        MFMA_P(1, bF1);
        __builtin_amdgcn_s_setprio(0);
        // counted drain: keep A(t+2) in flight; tail drains fully at t=NT-2
        if (t + 2 < NT)         asm volatile("s_waitcnt vmcnt(2)" ::: "memory");
        else if (t + 1 < NT)    asm volatile("s_waitcnt vmcnt(0)" ::: "memory");
        BAR();
    }

    // epilogue: fp32 row-major; both nt written temporally adjacent (128B/row WC)
    float bvs[2];
    #pragma unroll
    for (int nt = 0; nt < 2; ++nt) bvs[nt] = bias[tileN + wn * 32 + nt * 16 + l16];
    #pragma unroll
    for (int mt = 0; mt < 4; ++mt) {
        #pragma unroll
        for (int r = 0; r < 4; ++r) {
            const int rowg = tileM + wm * 64 + mt * 16 + quad * 4 + r;
            float* cp = C + (size_t)rowg * DIM + tileN + wn * 32 + l16;
            cp[0]  = acc[mt][0][r] + bvs[0];
            cp[16] = acc[mt][1][r] + bvs[1];
        }
    }
}

// ---- 8 bf16 (as uint4) -> 8 floats
__device__ __forceinline__ void bf8_to_f32(const uint4 u, float* f) {
    union { uint32_t u; float f; } c;
    c.u = u.x << 16;         f[0] = c.f;
    c.u = u.x & 0xffff0000u; f[1] = c.f;
    c.u = u.y << 16;         f[2] = c.f;
    c.u = u.y & 0xffff0000u; f[3] = c.f;
    c.u = u.z << 16;         f[4] = c.f;
    c.u = u.z & 0xffff0000u; f[5] = c.f;
    c.u = u.w << 16;         f[6] = c.f;
    c.u = u.w & 0xffff0000u; f[7] = c.f;
}

// Banded attention v4 over [b,h,s,t,d] qkv: 4 threads/query (16 dims each).
__global__ __launch_bounds__(256)
void attn_banded4(const bf16* __restrict__ qkv, bf16* __restrict__ aout) {
    const int tid = threadIdx.x;
    const int qi  = tid >> 2;          // 0..63
    const int ch  = tid & 3;           // 16-dim chunk
    const int t   = blockIdx.x * 64 + qi;
    const int h   = blockIdx.y;
    const int b   = blockIdx.z;

    const size_t bh3 = (size_t)(b * NHEAD + h) * 3;
    const bf16* qb = qkv + (bh3 + 0) * HSLICE + (size_t)t * HDIM + ch * 16;
    const bf16* kb = qkv + (bh3 + 1) * HSLICE + ch * 16;
    const bf16* vb = qkv + (bh3 + 2) * HSLICE + ch * 16;
    const float scale = 0.125f;        // hd^-0.5

    float q16[16];
    {
        const uint4* qp = (const uint4*)qb;
        uint4 u0 = qp[0], u1 = qp[1];
        bf8_to_f32(u0, q16); bf8_to_f32(u1, q16 + 8);
    }

    float sc[2 * RADIUS + 1];
    #pragma unroll
    for (int j = 0; j < 2 * RADIUS + 1; ++j) {
        const int k = t - RADIUS + j;
        const bool valid = (k >= 0) && (k < SEQ);
        const int kc = valid ? k : t;
        const uint4* kp = (const uint4*)(kb + (size_t)kc * HDIM);
        float kf[16];
        uint4 u0 = kp[0], u1 = kp[1];
        bf8_to_f32(u0, kf); bf8_to_f32(u1, kf + 8);
        float p = 0.f;
        #pragma unroll
        for (int e = 0; e < 16; ++e) p = fmaf(q16[e], kf[e], p);
        p += __shfl_xor(p, 1, 64);     // merge 4 chunks
        p += __shfl_xor(p, 2, 64);
        sc[j] = valid ? p * scale : -1e30f;
    }

    float mx = sc[0];
    #pragma unroll
    for (int j = 1; j < 2 * RADIUS + 1; ++j) mx = fmaxf(mx, sc[j]);
    float sum = 0.f;
    #pragma unroll
    for (int j = 0; j < 2 * RADIUS + 1; ++j) { sc[j] = __expf(sc[j] - mx); sum += sc[j]; }
    const float inv = 1.0f / sum;

    float o16[16];
    #pragma unroll
    for (int e = 0; e < 16; ++e) o16[e] = 0.f;
    #pragma unroll
    for (int j = 0; j < 2 * RADIUS + 1; ++j) {
        const int k = t - RADIUS + j;
        const int kc = (k >= 0 && k < SEQ) ? k : t;   // weight ~0 when clamped
        const uint4* vp = (const uint4*)(vb + (size_t)kc * HDIM);
        float vf[16];
        uint4 u0 = vp[0], u1 = vp[1];
        bf8_to_f32(u0, vf); bf8_to_f32(u1, vf + 8);
        const float w = sc[j];
        #pragma unroll
        for (int e = 0; e < 16; ++e) o16[e] = fmaf(w, vf[e], o16[e]);
    }

    bf16* op = aout + ((size_t)b * SEQ + t) * DIM + h * HDIM + ch * 16;
    #pragma unroll
    for (int c2 = 0; c2 < 2; ++c2) {
        union { u16x8 v; __hip_bfloat16 hh[8]; } o;
        #pragma unroll
        for (int e = 0; e < 8; ++e) o.hh[e] = __float2bfloat16(o16[c2 * 8 + e] * inv);
        ((u16x8*)op)[c2] = o.v;
    }
}

extern "C" void kernel_launch(void* const* d_in, const int* in_sizes, int n_in,
                              void* d_out, int out_size, void* d_ws, size_t ws_size,
                              hipStream_t stream) {
    const float* x      = (const float*)d_in[0];
    const float* w_qkv  = (const float*)d_in[1];
    const float* b_qkv  = (const float*)d_in[2];
    const float* w_proj = (const float*)d_in[3];
    const float* b_proj = (const float*)d_in[4];
    float* out = (float*)d_out;

    bf16* xb     = (bf16*)d_ws;
    bf16* wqkvb  = xb + (size_t)ROWS * DIM;
    bf16* wprojb = wqkvb + (size_t)3072 * 1024;
    bf16* qkvb   = wprojb + (size_t)1024 * 1024;   // [b,h,s,t,d], 48 MiB
    bf16* attnb  = qkvb + (size_t)ROWS * 3072;

    const int n1 = ROWS * DIM / 8, n2 = 3072 * 1024 / 8, n3 = 1024 * 1024 / 8;
    cvt_all<<<(n1 + n2 + n3 + 255) / 256, 256, 0, stream>>>(x, xb, n1, w_qkv, wqkvb, n2,
                                                            w_proj, wprojb, n3);

    // GEMM1: 4-wave 128x192 (per-wave 64x96), 1024 blocks, 2 blocks/CU, 2 rounds
    gemm_qkv_4w<<<dim3(1024), 256, 0, stream>>>(xb, wqkvb, b_qkv, qkvb);

    // attn v4: 4 threads/query, 32 waves/CU
    attn_banded4<<<dim3(SEQ / 64, NHEAD, BATCH), 256, 0, stream>>>(qkvb, attnb);

    // GEMM2: 2-phase 128x128, 512 blocks (64 Mtiles x 8 Ntiles), 2 blocks/CU
    gemm_proj_2b<<<dim3(512), 512, 0, stream>>>(attnb, wprojb, b_proj, out);
}